// Round 15
// baseline (626.247 us; speedup 1.0000x reference)
//
#include <hip/hip_runtime.h>

#define HID    128
#define GATES  512      // 4*HID
#define EMB    64
#define TSTEPS 1024
#define BATCH  512
#define VOCAB  50257
#define NCLS   28
#define TTAIL  4        // token tail pad: prefetch never needs a clamp

// gate pre-scale folded into proj and w_hh scales: i,f,o -> -log2e; g -> -2log2e
#define S_SIG  (-1.442695041f)
#define S_TANH (-2.885390082f)

typedef __attribute__((ext_vector_type(8))) short short8;   // 8 bf16 = 4 VGPRs
typedef __attribute__((ext_vector_type(4))) float f32x4;
typedef __attribute__((ext_vector_type(4))) unsigned short us4;
typedef __attribute__((ext_vector_type(4))) int int4v;

// lgkm-only barrier: LDS visibility without draining global (vmcnt) loads.
#define BAR_LGKM() __asm__ __volatile__("s_waitcnt lgkmcnt(0)\n\ts_barrier" ::: "memory")

static __device__ __forceinline__ float bf2f(unsigned short u){
  union { unsigned int i; float f; } v; v.i = ((unsigned int)u) << 16; return v.f;
}
static __device__ __forceinline__ unsigned short f2bf(float f){
  union { float ff; unsigned int i; } v; v.ff = f;
  unsigned int x = v.i;
  x += 0x7fffu + ((x >> 16) & 1u);   // round-to-nearest-even
  return (unsigned short)(x >> 16);
}

// ---------------------------------------------------------------------------
// Phase 1: proj[v][hcol][type] = s_type * (emb[v]·w_ih[g] + b_ih[g] + b_hh[g]),
// g = type*128 + hcol, stored bf16 interleaved. Verified (R11/R13/R14).
// ---------------------------------------------------------------------------
__global__ __launch_bounds__(256) void emb_proj_kernel(
    const float* __restrict__ emb,     // [V][64]
    const float* __restrict__ w_ih,    // [512][64]
    const float* __restrict__ b_ih,    // [512]
    const float* __restrict__ b_hh,    // [512]
    unsigned short* __restrict__ proj) // [V][512] interleaved bf16
{
  __shared__ float stage[16][516];     // [vrow][hcol*4+type], padded row

  int wave = threadIdx.x >> 6;         // 0..3 == gate type t
  int lane = threadIdx.x & 63;
  int n = lane & 15;
  int q = lane >> 4;
  long v0 = (long)blockIdx.x * 16;
  const float scl = (wave == 2) ? S_TANH : S_SIG;

  long vrow = v0 + n; if (vrow >= VOCAB) vrow = VOCAB - 1;
  const float* er = emb + vrow * EMB;
  short8 ahi[2], alo[2];
  #pragma unroll
  for (int ch = 0; ch < 2; ++ch){
    #pragma unroll
    for (int j = 0; j < 8; ++j){
      float xv = er[ch * 32 + q * 8 + j];
      unsigned short h = f2bf(xv);
      ahi[ch][j] = (short)h;
      alo[ch][j] = (short)f2bf(xv - bf2f(h));
    }
  }

  #pragma unroll
  for (int i = 0; i < 8; ++i){
    int g0 = (wave * 8 + i) * 16;               // gate base; type = wave
    const float* wr = w_ih + (long)(g0 + n) * EMB;
    short8 bhi[2], blo[2];
    #pragma unroll
    for (int ch = 0; ch < 2; ++ch){
      #pragma unroll
      for (int j = 0; j < 8; ++j){
        float xv = wr[ch * 32 + q * 8 + j];
        unsigned short h = f2bf(xv);
        bhi[ch][j] = (short)h;
        blo[ch][j] = (short)f2bf(xv - bf2f(h));
      }
    }
    float bias = b_ih[g0 + n] + b_hh[g0 + n];
    f32x4 acc = {bias, bias, bias, bias};
    #pragma unroll
    for (int ch = 0; ch < 2; ++ch){
      acc = __builtin_amdgcn_mfma_f32_16x16x32_bf16(ahi[ch], bhi[ch], acc, 0, 0, 0);
      acc = __builtin_amdgcn_mfma_f32_16x16x32_bf16(ahi[ch], blo[ch], acc, 0, 0, 0);
      acc = __builtin_amdgcn_mfma_f32_16x16x32_bf16(alo[ch], bhi[ch], acc, 0, 0, 0);
    }
    #pragma unroll
    for (int r = 0; r < 4; ++r)
      stage[q * 4 + r][(i * 16 + n) * 4 + wave] = scl * acc[r];
  }
  __syncthreads();

  {
    int row = threadIdx.x >> 4;          // 0..15
    int c0  = (threadIdx.x & 15) * 32;   // 0..480
    long grow = v0 + row;
    if (grow < VOCAB){
      unsigned short* dst = proj + grow * GATES + c0;
      #pragma unroll
      for (int k = 0; k < 8; ++k){
        us4 v;
        #pragma unroll
        for (int m = 0; m < 4; ++m) v[m] = f2bf(stage[row][c0 + k * 4 + m]);
        *(us4*)(dst + k * 4) = v;
      }
    }
  }
}

// ---------------------------------------------------------------------------
// Phase 2: LSTM recurrence, DE-PHASED PARTNER BLOCKS edition.
// 512 blocks x 256 threads (4 waves), R=1 row/block, 2 blocks/CU:
// the two co-resident blocks are independent recurrences with separate
// barriers -> one block's chain stalls (ds_read, exp2, barrier skew) are
// filled by the other block's issue. Cost: M-redundancy doubles chip MFMA
// (i8 pipe was 26% busy -> ~52%, affordable). Wave w owns hcols
// [w*32,w*32+32) as tiles (t, s in {0,1}) = 16 i8 MFMA/wave. A = broadcast
// h (R=1 -> all C rows duplicate) -> every lane owns cell hcol =
// w*32 + (q&1)*16 + n in acc[t][q&1] reg0; in-register nonlinearity;
// q<2 lanes write h. One lgkm-only 4-wave barrier per step.
// ---------------------------------------------------------------------------
__global__ __launch_bounds__(256, 2) void lstm_kernel(
    const int* __restrict__ x,           // [512][1024] int32
    const float* __restrict__ w_hh,      // [512][128] f32
    const unsigned short* __restrict__ proj, // [V][512] bf16 interleaved
    const float* __restrict__ w_lin,     // [28][128] f32
    const float* __restrict__ b_lin,     // [28] f32
    float* __restrict__ out)             // [512][28] f32
{
  __shared__ int tok_lds[TSTEPS + TTAIL];      // tok*GATES
  __shared__ signed char h8[2][160];           // [buf][hcol] i8 h, padded

  int tid  = threadIdx.x;
  int wave = tid >> 6;          // 0..3
  int lane = tid & 63;
  int n = lane & 15;
  int q = lane >> 4;
  int sI = q & 1;               // this lane's owned s-slice
  int r0 = blockIdx.x;          // batch row

  // --- preload tokens (pre-multiplied element offsets) ------------------
  for (int i = tid; i < TSTEPS + TTAIL; i += 256){
    int src = i < TSTEPS ? i : TSTEPS - 1;
    tok_lds[i] = x[(long)r0 * TSTEPS + src] * GATES;
  }

  // --- quantize w_hh to i8, per-gate-row max scale ----------------------
  // tile (t,s): gate row = t*128 + wave*32 + s*16 + n; B[k=ch*64+q*16+j][n]
  int4v Bw[4][2][2];            // [t][s][ch]
  float scl[4];                 // dequant scale for own cell (s = sI)
  #pragma unroll
  for (int t = 0; t < 4; ++t){
    #pragma unroll
    for (int s = 0; s < 2; ++s){
      int row = t * 128 + wave * 32 + s * 16 + n;
      const float* wr = w_hh + (long)row * HID;
      float vals[2][16];
      float m = 0.f;
      #pragma unroll
      for (int ch = 0; ch < 2; ++ch)
        #pragma unroll
        for (int j = 0; j < 16; ++j){
          float v = wr[ch * 64 + q * 16 + j];
          vals[ch][j] = v;
          m = fmaxf(m, fabsf(v));
        }
      m = fmaxf(m, __shfl_xor(m, 16, 64));
      m = fmaxf(m, __shfl_xor(m, 32, 64));
      m = fmaxf(m, 1e-20f);
      float qs = 127.f / m;
      #pragma unroll
      for (int ch = 0; ch < 2; ++ch){
        #pragma unroll
        for (int d = 0; d < 4; ++d){
          int b0 = (int)__builtin_rintf(vals[ch][d * 4 + 0] * qs);
          int b1 = (int)__builtin_rintf(vals[ch][d * 4 + 1] * qs);
          int b2 = (int)__builtin_rintf(vals[ch][d * 4 + 2] * qs);
          int b3 = (int)__builtin_rintf(vals[ch][d * 4 + 3] * qs);
          Bw[t][s][ch] = Bw[t][s][ch];  // keep array form
          Bw[t][s][ch][d] = (b0 & 255) | ((b1 & 255) << 8) | ((b2 & 255) << 16) | (b3 << 24);
        }
      }
      if (s == sI)
        scl[t] = ((t == 2) ? S_TANH : S_SIG) * m * (1.f / 16129.f);  // /127^2
    }
  }

  // zero h buffers (h0 = 0)
  for (int i = tid; i < 2 * 160; i += 256) ((signed char*)h8)[i] = 0;

  float c_state = 0.f;                   // every lane owns one cell (2x dup)
  bool  hwr = (q < 2);                   // unique owners write h
  int   hcol = wave * 32 + sI * 16 + n;  // this lane's cell

  int4v acc[4][2] = {};                  // reg0 re-zeroed per step; 1-3 garbage
  int ghcol4 = hcol * 4;                 // element offset within a proj row

  __syncthreads();                       // tokens + h zeros

  // --- depth-2 gx prefetch ----------------------------------------------
  us4 hxA, hxB;
  hxA = *(const us4*)(proj + (long)(tok_lds[0] + ghcol4));
  hxB = *(const us4*)(proj + (long)(tok_lds[1] + ghcol4));

#define GATE_TILE(T, HXC, GV, EV, CLAMP)                                      \
    acc[T][0][0] = 0; acc[T][1][0] = 0;                                       \
    acc[T][0] = __builtin_amdgcn_mfma_i32_16x16x64_i8(Af0, Bw[T][0][0], acc[T][0], 0, 0, 0); \
    acc[T][0] = __builtin_amdgcn_mfma_i32_16x16x64_i8(Af1, Bw[T][0][1], acc[T][0], 0, 0, 0); \
    acc[T][1] = __builtin_amdgcn_mfma_i32_16x16x64_i8(Af0, Bw[T][1][0], acc[T][1], 0, 0, 0); \
    acc[T][1] = __builtin_amdgcn_mfma_i32_16x16x64_i8(Af1, Bw[T][1][1], acc[T][1], 0, 0, 0); \
    {                                                                         \
      float gv = (float)(sI ? acc[T][1][0] : acc[T][0][0]) * scl[T]           \
                 + bf2f(HXC[T]);                                              \
      EV = __builtin_amdgcn_exp2f(CLAMP ? fminf(gv, 126.f) : gv);             \
    }

#define SUBSTEP(RB, HX, NSTEP)                                                \
  {                                                                           \
    int4v Af0 = *(const int4v*)(&h8[RB][q * 16]);                             \
    int4v Af1 = *(const int4v*)(&h8[RB][64 + q * 16]);                        \
    us4 hx_cur = HX;                                                          \
    HX = *(const us4*)(proj + (long)(tok_lds[NSTEP] + ghcol4));               \
    float ef, ei, eg, eo;                                                     \
    GATE_TILE(1, hx_cur, g1, ef, 0)      /* f first: c_state needs sf */      \
    float sf = __builtin_amdgcn_rcpf(1.f + ef);                               \
    GATE_TILE(0, hx_cur, g0, ei, 0)                                           \
    GATE_TILE(2, hx_cur, g2, eg, 1)                                           \
    GATE_TILE(3, hx_cur, g3, eo, 0)                                           \
    float r1 = __builtin_amdgcn_rcpf((1.f + ei) * (1.f + eg));                \
    float sitg = (1.f - eg) * r1;             /* si * tg */                   \
    c_state = sf * c_state + sitg;                                            \
    float ec = __builtin_amdgcn_exp2f(fminf(S_TANH * c_state, 126.f));        \
    float r2 = __builtin_amdgcn_rcpf((1.f + eo) * (1.f + ec));                \
    float hv = (1.f - ec) * r2;               /* tanh(c) * so */              \
    if (hwr)                                                                  \
      h8[(RB) ^ 1][hcol] = (signed char)(int)__builtin_rintf(hv * 127.f);     \
    BAR_LGKM();                                                               \
  }

  for (int step = 0; step < TSTEPS; step += 2){
    SUBSTEP(0, hxA, step + 2)
    SUBSTEP(1, hxB, step + 3)
  }
#undef SUBSTEP
#undef GATE_TILE

  // --- final linear: out[r0][j] = (qh/127) . w_lin[j] + b_lin[j] --------
  // TSTEPS even -> final h is in h8[0]
  if (tid < NCLS){
    int j = tid;
    float s = 0.f;
    const float* wl = w_lin + (long)j * HID;
    #pragma unroll 4
    for (int k = 0; k < HID; ++k)
      s += (float)h8[0][k] * wl[k];
    out[(long)r0 * NCLS + j] = b_lin[j] + s * (1.f / 127.f);
  }
}

// ---------------------------------------------------------------------------
extern "C" void kernel_launch(void* const* d_in, const int* in_sizes, int n_in,
                              void* d_out, int out_size, void* d_ws, size_t ws_size,
                              hipStream_t stream)
{
  const int*   x     = (const int*)d_in[0];
  const float* emb   = (const float*)d_in[1];
  const float* w_ih  = (const float*)d_in[2];
  const float* w_hh  = (const float*)d_in[3];
  const float* b_ih  = (const float*)d_in[4];
  const float* b_hh  = (const float*)d_in[5];
  const float* w_lin = (const float*)d_in[6];
  const float* b_lin = (const float*)d_in[7];
  float*       out   = (float*)d_out;
  unsigned short* proj = (unsigned short*)d_ws;   // [V][512] bf16, ~51.5 MB

  int vblocks = (VOCAB + 15) / 16;   // 3142
  emb_proj_kernel<<<dim3(vblocks), dim3(256), 0, stream>>>(
      emb, w_ih, b_ih, b_hh, proj);
  lstm_kernel<<<dim3(BATCH), dim3(256), 0, stream>>>(
      x, w_hh, proj, w_lin, b_lin, out);
}

// Round 16
// 501.456 us; speedup vs baseline: 1.2489x; 1.2489x over previous
//
#include <hip/hip_runtime.h>

#define HID    128
#define GATES  512      // 4*HID
#define EMB    64
#define TSTEPS 1024
#define BATCH  512
#define VOCAB  50257
#define NCLS   28
#define H8STRIDE 160    // h row stride in BYTES (i8 h)
#define TPAD   8        // token row pad (ints)
#define TTAIL  4        // token tail pad: prefetch never needs a clamp

// gate pre-scale folded into proj and w_hh scales: i,f,o -> -log2e; g -> -2log2e
#define S_SIG  (-1.442695041f)
#define S_TANH (-2.885390082f)

typedef __attribute__((ext_vector_type(8))) short short8;   // 8 bf16 = 4 VGPRs
typedef __attribute__((ext_vector_type(4))) float f32x4;
typedef __attribute__((ext_vector_type(4))) unsigned short us4;
typedef __attribute__((ext_vector_type(4))) int int4v;

// lgkm-only barrier: LDS visibility without draining global (vmcnt) loads.
#define BAR_LGKM() __asm__ __volatile__("s_waitcnt lgkmcnt(0)\n\ts_barrier" ::: "memory")

static __device__ __forceinline__ float bf2f(unsigned short u){
  union { unsigned int i; float f; } v; v.i = ((unsigned int)u) << 16; return v.f;
}
static __device__ __forceinline__ unsigned short f2bf(float f){
  union { float ff; unsigned int i; } v; v.ff = f;
  unsigned int x = v.i;
  x += 0x7fffu + ((x >> 16) & 1u);   // round-to-nearest-even
  return (unsigned short)(x >> 16);
}

// ---------------------------------------------------------------------------
// Phase 1: proj[v][hcol][type] = s_type * (emb[v]·w_ih[g] + b_ih[g] + b_hh[g]),
// g = type*128 + hcol, stored bf16 interleaved. Verified (R11/R13/R14).
// ---------------------------------------------------------------------------
__global__ __launch_bounds__(256) void emb_proj_kernel(
    const float* __restrict__ emb,     // [V][64]
    const float* __restrict__ w_ih,    // [512][64]
    const float* __restrict__ b_ih,    // [512]
    const float* __restrict__ b_hh,    // [512]
    unsigned short* __restrict__ proj) // [V][512] interleaved bf16
{
  __shared__ float stage[16][516];     // [vrow][hcol*4+type], padded row

  int wave = threadIdx.x >> 6;         // 0..3 == gate type t
  int lane = threadIdx.x & 63;
  int n = lane & 15;
  int q = lane >> 4;
  long v0 = (long)blockIdx.x * 16;
  const float scl = (wave == 2) ? S_TANH : S_SIG;

  long vrow = v0 + n; if (vrow >= VOCAB) vrow = VOCAB - 1;
  const float* er = emb + vrow * EMB;
  short8 ahi[2], alo[2];
  #pragma unroll
  for (int ch = 0; ch < 2; ++ch){
    #pragma unroll
    for (int j = 0; j < 8; ++j){
      float xv = er[ch * 32 + q * 8 + j];
      unsigned short h = f2bf(xv);
      ahi[ch][j] = (short)h;
      alo[ch][j] = (short)f2bf(xv - bf2f(h));
    }
  }

  #pragma unroll
  for (int i = 0; i < 8; ++i){
    int g0 = (wave * 8 + i) * 16;               // gate base; type = wave
    const float* wr = w_ih + (long)(g0 + n) * EMB;
    short8 bhi[2], blo[2];
    #pragma unroll
    for (int ch = 0; ch < 2; ++ch){
      #pragma unroll
      for (int j = 0; j < 8; ++j){
        float xv = wr[ch * 32 + q * 8 + j];
        unsigned short h = f2bf(xv);
        bhi[ch][j] = (short)h;
        blo[ch][j] = (short)f2bf(xv - bf2f(h));
      }
    }
    float bias = b_ih[g0 + n] + b_hh[g0 + n];
    f32x4 acc = {bias, bias, bias, bias};
    #pragma unroll
    for (int ch = 0; ch < 2; ++ch){
      acc = __builtin_amdgcn_mfma_f32_16x16x32_bf16(ahi[ch], bhi[ch], acc, 0, 0, 0);
      acc = __builtin_amdgcn_mfma_f32_16x16x32_bf16(ahi[ch], blo[ch], acc, 0, 0, 0);
      acc = __builtin_amdgcn_mfma_f32_16x16x32_bf16(alo[ch], bhi[ch], acc, 0, 0, 0);
    }
    #pragma unroll
    for (int r = 0; r < 4; ++r)
      stage[q * 4 + r][(i * 16 + n) * 4 + wave] = scl * acc[r];
  }
  __syncthreads();

  {
    int row = threadIdx.x >> 4;          // 0..15
    int c0  = (threadIdx.x & 15) * 32;   // 0..480
    long grow = v0 + row;
    if (grow < VOCAB){
      unsigned short* dst = proj + grow * GATES + c0;
      #pragma unroll
      for (int k = 0; k < 8; ++k){
        us4 v;
        #pragma unroll
        for (int m = 0; m < 4; ++m) v[m] = f2bf(stage[row][c0 + k * 4 + m]);
        *(us4*)(dst + k * 4) = v;
      }
    }
  }
}

// ---------------------------------------------------------------------------
// Phase 2: LSTM recurrence + final linear. R14 structure (best measured:
// 439 µs) + final micro-trims: (1) zero-C MFMA — loop-invariant zero vector
// as the C operand of each tile's first MFMA (no per-substep acc zeroing,
// no loop-carried register dependency); (2) gx bf16->f32 shifts hoisted off
// the dequant chain; (3) per-tile local accumulators.
// 256 blocks x 512 threads, R=2, 2 waves/SIMD, i8 16x16x64 MFMA (8/wave),
// per-gate-row max-scaled w_hh, all-lane nonlin via C-row duplicates,
// one lgkm-only barrier per step, depth-2 dwordx2 gx prefetch.
// ---------------------------------------------------------------------------
__global__ __launch_bounds__(512, 2) void lstm_kernel(
    const int* __restrict__ x,           // [512][1024] int32
    const float* __restrict__ w_hh,      // [512][128] f32
    const unsigned short* __restrict__ proj, // [V][512] bf16 interleaved
    const float* __restrict__ w_lin,     // [28][128] f32
    const float* __restrict__ b_lin,     // [28] f32
    float* __restrict__ out)             // [512][28] f32
{
  __shared__ int   tok_lds[2][TSTEPS + TPAD];   // tok*GATES, bank-padded
  __shared__ signed char h8[2][2][H8STRIDE];    // [buf][row][hcol] i8 h

  int tid  = threadIdx.x;
  int wave = tid >> 6;          // 0..7
  int lane = tid & 63;
  int n = lane & 15;
  int q = lane >> 4;
  int r0 = blockIdx.x * 2;

  // --- preload tokens (pre-multiplied element offsets) ------------------
  for (int i = tid; i < TSTEPS + TTAIL; i += 512){
    int src = i < TSTEPS ? i : TSTEPS - 1;
    tok_lds[0][i] = x[(long)r0 * TSTEPS + src] * GATES;
    tok_lds[1][i] = x[(long)(r0 + 1) * TSTEPS + src] * GATES;
  }

  // --- quantize w_hh to i8, per-gate-row max scale ----------------------
  // tile t: gate row = t*128 + wave*16 + n; B[k = ch*64 + q*16 + j][n]
  int4v Bw[4][2];
  float scl[4];
  #pragma unroll
  for (int t = 0; t < 4; ++t){
    int row = t * 128 + wave * 16 + n;
    const float* wr = w_hh + (long)row * HID;
    float vals[2][16];
    float m = 0.f;
    #pragma unroll
    for (int ch = 0; ch < 2; ++ch)
      #pragma unroll
      for (int j = 0; j < 16; ++j){
        float v = wr[ch * 64 + q * 16 + j];
        vals[ch][j] = v;
        m = fmaxf(m, fabsf(v));
      }
    m = fmaxf(m, __shfl_xor(m, 16, 64));
    m = fmaxf(m, __shfl_xor(m, 32, 64));
    m = fmaxf(m, 1e-20f);
    float qs = 127.f / m;
    #pragma unroll
    for (int ch = 0; ch < 2; ++ch){
      #pragma unroll
      for (int d = 0; d < 4; ++d){
        int b0 = (int)__builtin_rintf(vals[ch][d * 4 + 0] * qs);
        int b1 = (int)__builtin_rintf(vals[ch][d * 4 + 1] * qs);
        int b2 = (int)__builtin_rintf(vals[ch][d * 4 + 2] * qs);
        int b3 = (int)__builtin_rintf(vals[ch][d * 4 + 3] * qs);
        Bw[t][ch][d] = (b0 & 255) | ((b1 & 255) << 8) | ((b2 & 255) << 16) | (b3 << 24);
      }
    }
    scl[t] = ((t == 2) ? S_TANH : S_SIG) * m * (1.f / 16129.f);  // /127^2
  }

  // zero h buffers (h0 = 0)
  for (int i = tid; i < 2 * 2 * H8STRIDE; i += 512) ((signed char*)h8)[i] = 0;

  float c_state = 0.f;                   // q0/q2: row0 cell; q1/q3: row1 (dups)
  bool  nlact = (q < 2);                 // unique owners write h
  int   arow  = (n >> 2) & 1;            // h row this lane supplies to A
  int   grow  = q & 1;                   // gx row this lane gathers
  int   hcol  = wave * 16 + n;

  const int4v ZERO4 = {0, 0, 0, 0};      // loop-invariant MFMA C operand
  int ghcol4 = hcol * 4;                 // element offset within a proj row

  __syncthreads();                       // tokens + h zeros

  // --- depth-2 gx prefetch ----------------------------------------------
  us4 hxA, hxB;
  hxA = *(const us4*)(proj + (long)(tok_lds[grow][0] + ghcol4));
  hxB = *(const us4*)(proj + (long)(tok_lds[grow][1] + ghcol4));

#define SUBSTEP(RB, HX, NSTEP)                                                \
  {                                                                           \
    int4v Af0 = *(const int4v*)(&h8[RB][arow][q * 16]);                       \
    int4v Af1 = *(const int4v*)(&h8[RB][arow][64 + q * 16]);                  \
    /* hoist gx bf16->f32 off the dequant chain */                            \
    float gx0 = bf2f(HX[0]), gx1 = bf2f(HX[1]);                               \
    float gx2 = bf2f(HX[2]), gx3 = bf2f(HX[3]);                               \
    HX = *(const us4*)(proj + (long)(tok_lds[grow][NSTEP] + ghcol4));         \
    /* f-gate tile first: c_state needs sf earliest */                        \
    int4v a1 = __builtin_amdgcn_mfma_i32_16x16x64_i8(Af0, Bw[1][0], ZERO4, 0, 0, 0); \
    a1 = __builtin_amdgcn_mfma_i32_16x16x64_i8(Af1, Bw[1][1], a1, 0, 0, 0);   \
    float g1 = (float)a1[0] * scl[1] + gx1;                                   \
    float ef = __builtin_amdgcn_exp2f(g1);                                    \
    float sf = __builtin_amdgcn_rcpf(1.f + ef);                               \
    int4v a0 = __builtin_amdgcn_mfma_i32_16x16x64_i8(Af0, Bw[0][0], ZERO4, 0, 0, 0); \
    a0 = __builtin_amdgcn_mfma_i32_16x16x64_i8(Af1, Bw[0][1], a0, 0, 0, 0);   \
    float g0 = (float)a0[0] * scl[0] + gx0;                                   \
    float ei = __builtin_amdgcn_exp2f(g0);                                    \
    int4v a2 = __builtin_amdgcn_mfma_i32_16x16x64_i8(Af0, Bw[2][0], ZERO4, 0, 0, 0); \
    a2 = __builtin_amdgcn_mfma_i32_16x16x64_i8(Af1, Bw[2][1], a2, 0, 0, 0);   \
    float g2 = (float)a2[0] * scl[2] + gx2;                                   \
    float eg = __builtin_amdgcn_exp2f(fminf(g2, 126.f));                      \
    int4v a3 = __builtin_amdgcn_mfma_i32_16x16x64_i8(Af0, Bw[3][0], ZERO4, 0, 0, 0); \
    a3 = __builtin_amdgcn_mfma_i32_16x16x64_i8(Af1, Bw[3][1], a3, 0, 0, 0);   \
    float g3 = (float)a3[0] * scl[3] + gx3;                                   \
    float eo = __builtin_amdgcn_exp2f(g3);                                    \
    float r1 = __builtin_amdgcn_rcpf((1.f + ei) * (1.f + eg));                \
    float sitg = (1.f - eg) * r1;             /* si * tg */                   \
    c_state = sf * c_state + sitg;                                            \
    float ec = __builtin_amdgcn_exp2f(fminf(S_TANH * c_state, 126.f));        \
    float r2 = __builtin_amdgcn_rcpf((1.f + eo) * (1.f + ec));                \
    float hv = (1.f - ec) * r2;               /* tanh(c) * so */              \
    if (nlact)                                                                \
      h8[(RB) ^ 1][q][hcol] = (signed char)(int)__builtin_rintf(hv * 127.f);  \
    BAR_LGKM();                                                               \
  }

  for (int step = 0; step < TSTEPS; step += 2){
    SUBSTEP(0, hxA, step + 2)
    SUBSTEP(1, hxB, step + 3)
  }
#undef SUBSTEP

  // --- final linear: out[r0+b][j] = (qh[b]/127) . w_lin[j] + b_lin[j] ---
  // TSTEPS even -> final h is in h8[0]
  if (tid < 2 * NCLS){
    int b = tid / NCLS, j = tid - b * NCLS;
    float s = 0.f;
    const float* wl = w_lin + (long)j * HID;
    #pragma unroll 4
    for (int k = 0; k < HID; ++k)
      s += (float)h8[0][b][k] * wl[k];
    out[(long)(r0 + b) * NCLS + j] = b_lin[j] + s * (1.f / 127.f);
  }
}

// ---------------------------------------------------------------------------
extern "C" void kernel_launch(void* const* d_in, const int* in_sizes, int n_in,
                              void* d_out, int out_size, void* d_ws, size_t ws_size,
                              hipStream_t stream)
{
  const int*   x     = (const int*)d_in[0];
  const float* emb   = (const float*)d_in[1];
  const float* w_ih  = (const float*)d_in[2];
  const float* w_hh  = (const float*)d_in[3];
  const float* b_ih  = (const float*)d_in[4];
  const float* b_hh  = (const float*)d_in[5];
  const float* w_lin = (const float*)d_in[6];
  const float* b_lin = (const float*)d_in[7];
  float*       out   = (float*)d_out;
  unsigned short* proj = (unsigned short*)d_ws;   // [V][512] bf16, ~51.5 MB

  int vblocks = (VOCAB + 15) / 16;   // 3142
  emb_proj_kernel<<<dim3(vblocks), dim3(256), 0, stream>>>(
      emb, w_ih, b_ih, b_hh, proj);
  lstm_kernel<<<dim3(BATCH / 2), dim3(512), 0, stream>>>(
      x, w_hh, proj, w_lin, b_lin, out);
}